// Round 2
// baseline (3473.131 us; speedup 1.0000x reference)
//
#include <hip/hip_runtime.h>
#include <stdint.h>
#include <stddef.h>

#define B_    64
#define T_    16
#define DF_   512
#define S_    196
#define DIN_  512
#define H_    8
#define DH_   64
#define DM_   1024
#define MEM_  25
#define HN_   32
#define NSA_  512
#define NSO_  512
#define DOUT_ 512
#define MR_   (B_*S_)   /* 12544 */

typedef short bf16x8 __attribute__((ext_vector_type(8)));
typedef float f32x4  __attribute__((ext_vector_type(4)));

__device__ __forceinline__ float b2f(short h){
  unsigned u = ((unsigned)(unsigned short)h) << 16;
  float f; __builtin_memcpy(&f, &u, 4); return f;
}
__device__ __forceinline__ short f2b(float f){
  unsigned u; __builtin_memcpy(&u, &f, 4);
  u = (u + 0x7fffu + ((u >> 16) & 1u)) >> 16;
  return (short)(unsigned short)u;
}
__device__ __forceinline__ float clip015(float d){
  return d < 0.f ? 0.f : (d > 15.f ? 15.f : d);
}

// ---------------------------------------------------------------------------
// Generic bf16 MFMA GEMM: C[M,N] = A[M,K] @ W[K,N] + bias, W given as WT[N,K]
// (both bf16). Bias f32. 128x128 tile, BK=64, 4 waves (2x2), 16x16x32 MFMA,
// global_load_lds width-16 staging with XOR chunk swizzle (T21: linear LDS
// dest + inverse-swizzled global source + swizzled read).
// ---------------------------------------------------------------------------
template<int OUTF32>
__global__ __launch_bounds__(256,2) void gemm_k(
    const short* __restrict__ A, const short* __restrict__ WT,
    void* __restrict__ Cout,
    const float* __restrict__ biasA, const float* __restrict__ biasB, int nsplit,
    int M, int N, int K)
{
  __shared__ short lA[128*64];
  __shared__ short lB[128*64];
  const int tid = threadIdx.x;
  const int w = tid >> 6, l = tid & 63;
  const int m0 = blockIdx.x * 128, n0 = blockIdx.y * 128;
  const int wm = (w >> 1) * 64, wn = (w & 1) * 64;
  f32x4 acc[4][4];
  #pragma unroll
  for (int i=0;i<4;i++)
    #pragma unroll
    for (int j=0;j<4;j++) acc[i][j] = (f32x4){0.f,0.f,0.f,0.f};

  for (int k0 = 0; k0 < K; k0 += 64) {
    #pragma unroll
    for (int rnd = 0; rnd < 4; ++rnd) {
      int cb = (rnd*4 + w) * 64;          // chunk base for this wave-inst
      int slot = cb + l;                   // linear 16B-chunk slot
      int row = slot >> 3, kb = slot & 7;
      int kc = k0 + ((kb ^ (row & 7)) << 3);   // pre-swizzled source column
      int gm = m0 + row; if (gm > M-1) gm = M-1;
      const short* srcA = A + (size_t)gm * K + kc;
      __builtin_amdgcn_global_load_lds(
          (const __attribute__((address_space(1))) void*)srcA,
          (__attribute__((address_space(3))) void*)&lA[cb*8], 16, 0, 0);
      const short* srcB = WT + (size_t)(n0 + row) * K + kc;
      __builtin_amdgcn_global_load_lds(
          (const __attribute__((address_space(1))) void*)srcB,
          (__attribute__((address_space(3))) void*)&lB[cb*8], 16, 0, 0);
    }
    asm volatile("s_waitcnt vmcnt(0)" ::: "memory");
    __syncthreads();
    #pragma unroll
    for (int ks = 0; ks < 2; ++ks) {
      bf16x8 af[4], bfr[4];
      #pragma unroll
      for (int i = 0; i < 4; ++i) {
        int ra = wm + i*16 + (l & 15);
        int c  = ks*4 + (l >> 4);
        af[i]  = *(const bf16x8*)&lA[ra*64 + ((c ^ (ra & 7)) << 3)];
        int rb = wn + i*16 + (l & 15);
        bfr[i] = *(const bf16x8*)&lB[rb*64 + ((c ^ (rb & 7)) << 3)];
      }
      #pragma unroll
      for (int i = 0; i < 4; ++i)
        #pragma unroll
        for (int j = 0; j < 4; ++j)
          acc[i][j] = __builtin_amdgcn_mfma_f32_16x16x32_bf16(af[i], bfr[j], acc[i][j], 0, 0, 0);
    }
    __syncthreads();
  }
  #pragma unroll
  for (int i = 0; i < 4; ++i) {
    #pragma unroll
    for (int j = 0; j < 4; ++j) {
      int gn = n0 + wn + j*16 + (l & 15);
      float bb = (gn < nsplit) ? biasA[gn] : biasB[gn - nsplit];
      #pragma unroll
      for (int r = 0; r < 4; ++r) {
        int gm = m0 + wm + i*16 + (l >> 4)*4 + r;
        if (gm < M) {
          float v = acc[i][j][r] + bb;
          if (OUTF32) ((float*)Cout)[(size_t)gm * N + gn] = v;
          else        ((short*)Cout)[(size_t)gm * N + gn] = f2b(v);
        }
      }
    }
  }
}

// ---------------------------------------------------------------------------
// Per-tick transpose of x[:,t]: f32 [B][DF][S] -> bf16 xT [(b*S+s)][DF]
// ---------------------------------------------------------------------------
__global__ __launch_bounds__(256) void xpose_x(const float* __restrict__ x,
                                               short* __restrict__ xT, int t)
{
  __shared__ float tile[32][33];
  int df0 = blockIdx.x*32, s0 = blockIdx.y*32, b = blockIdx.z;
  int tx = threadIdx.x & 31, ty = threadIdx.x >> 5;
  const float* src = x + (size_t)(b*T_ + t) * DF_ * S_;
  #pragma unroll
  for (int i = 0; i < 4; ++i) {
    int df = df0 + ty + i*8;
    int s  = s0 + tx;
    tile[ty+i*8][tx] = (s < S_) ? src[(size_t)df*S_ + s] : 0.f;
  }
  __syncthreads();
  short* dst = xT + (size_t)b * S_ * DIN_;
  #pragma unroll
  for (int i = 0; i < 4; ++i) {
    int s  = s0 + ty + i*8;
    int df = df0 + tx;
    if (s < S_) dst[(size_t)s*DF_ + df] = f2b(tile[tx][ty+i*8]);
  }
}

// Weight transpose + f32->bf16 (dims multiples of 32): out[C][R] = in[R][C]
__global__ __launch_bounds__(256) void wtrans(const float* __restrict__ in,
                                              short* __restrict__ out, int R, int C)
{
  __shared__ float tile[32][33];
  int c0 = blockIdx.x*32, r0 = blockIdx.y*32;
  int tx = threadIdx.x & 31, ty = threadIdx.x >> 5;
  #pragma unroll
  for (int i = 0; i < 4; ++i)
    tile[ty+i*8][tx] = in[(size_t)(r0+ty+i*8)*C + c0+tx];
  __syncthreads();
  #pragma unroll
  for (int i = 0; i < 4; ++i)
    out[(size_t)(c0+ty+i*8)*R + r0+tx] = f2b(tile[tx][ty+i*8]);
}

// ---------------------------------------------------------------------------
// Row LayerNorm over 512 cols: f32 in -> bf16 out. One wave per row.
// ---------------------------------------------------------------------------
__global__ __launch_bounds__(256) void ln_rows(const float* __restrict__ in,
    const float* __restrict__ g, const float* __restrict__ bta,
    short* __restrict__ out, int nrows)
{
  int w = threadIdx.x >> 6, l = threadIdx.x & 63;
  int r = blockIdx.x*4 + w;
  if (r >= nrows) return;
  const float* row = in + (size_t)r * 512;
  float v[8]; float s = 0.f, s2 = 0.f;
  #pragma unroll
  for (int j = 0; j < 8; ++j) { v[j] = row[l*8+j]; s += v[j]; s2 += v[j]*v[j]; }
  #pragma unroll
  for (int m = 1; m < 64; m <<= 1) { s += __shfl_xor(s, m, 64); s2 += __shfl_xor(s2, m, 64); }
  float mean = s * (1.f/512.f);
  float var  = s2 * (1.f/512.f) - mean*mean;
  float inv  = rsqrtf(var + 1e-5f);
  bf16x8 o8;
  #pragma unroll
  for (int j = 0; j < 8; ++j) {
    float y = (v[j] - mean) * inv * g[l*8+j] + bta[l*8+j];
    o8[j] = f2b(y);
  }
  *(bf16x8*)&out[(size_t)r*512 + l*8] = o8;
}

// ---------------------------------------------------------------------------
// sync_a update + q = sync@Wqp + bqp, qh = q@Wq + bq. One block per b.
// ---------------------------------------------------------------------------
__global__ __launch_bounds__(256) void s1_q(const float* __restrict__ actT,
    float* __restrict__ aa, float* __restrict__ ba,
    const int* __restrict__ li, const int* __restrict__ ri,
    const float* __restrict__ decay,
    const float* __restrict__ Wqp, const float* __restrict__ bqp,
    const float* __restrict__ Wq,  const float* __restrict__ bq,
    float* __restrict__ qh)
{
  __shared__ float syncL[512];
  __shared__ float qL[512];
  int b = blockIdx.x, tid = threadIdx.x;
  for (int j = tid; j < 512; j += 256) {
    float r = expf(-clip015(decay[j]));
    float prod = actT[li[j]*64 + b] * actT[ri[j]*64 + b];
    float a  = r*aa[b*512+j] + prod; aa[b*512+j] = a;
    float bb = r*ba[b*512+j] + 1.f;  ba[b*512+j] = bb;
    syncL[j] = a * rsqrtf(bb);
  }
  __syncthreads();
  {
    int n0 = tid, n1 = tid + 256;
    float a0 = 0.f, a1 = 0.f;
    #pragma unroll 8
    for (int k = 0; k < 512; ++k) {
      float sv = syncL[k];
      a0 += sv * Wqp[k*512+n0];
      a1 += sv * Wqp[k*512+n1];
    }
    qL[n0] = a0 + bqp[n0];
    qL[n1] = a1 + bqp[n1];
  }
  __syncthreads();
  {
    int n0 = tid, n1 = tid + 256;
    float a0 = 0.f, a1 = 0.f;
    #pragma unroll 8
    for (int k = 0; k < 512; ++k) {
      float qv = qL[k];
      a0 += qv * Wq[k*512+n0];
      a1 += qv * Wq[k*512+n1];
    }
    qh[b*512+n0] = a0 + bq[n0];
    qh[b*512+n1] = a1 + bq[n1];
  }
}

// ---------------------------------------------------------------------------
// Attention for one (h,b): scores(196) -> softmax -> PV. KV holds [K|V] bf16.
// ---------------------------------------------------------------------------
__global__ __launch_bounds__(256) void attn_k(const float* __restrict__ qh,
    const short* __restrict__ KV, float* __restrict__ o)
{
  __shared__ float qv[64];
  __shared__ float scL[256];
  __shared__ float red[2];
  __shared__ float pv[4][64];
  int h = blockIdx.x, b = blockIdx.y, tid = threadIdx.x;
  if (tid < 64) qv[tid] = qh[b*512 + h*64 + tid];
  __syncthreads();
  float sc = -1e30f;
  if (tid < S_) {
    const short* kp = KV + ((size_t)(b*S_ + tid)*1024 + h*64);
    float s = 0.f;
    #pragma unroll
    for (int c = 0; c < 8; ++c) {
      bf16x8 kk = *(const bf16x8*)&kp[c*8];
      #pragma unroll
      for (int j = 0; j < 8; ++j) s += qv[c*8+j] * b2f(kk[j]);
    }
    sc = s * 0.125f;   // 1/sqrt(64)
  }
  scL[tid] = sc;
  __syncthreads();
  if (tid < 64) {
    float m = fmaxf(fmaxf(scL[tid], scL[tid+64]), fmaxf(scL[tid+128], scL[tid+192]));
    #pragma unroll
    for (int k = 32; k >= 1; k >>= 1) m = fmaxf(m, __shfl_xor(m, k, 64));
    if (tid == 0) red[0] = m;
  }
  __syncthreads();
  float M = red[0];
  float p = (tid < S_) ? expf(sc - M) : 0.f;
  scL[tid] = p;
  __syncthreads();
  if (tid < 64) {
    float s = scL[tid] + scL[tid+64] + scL[tid+128] + scL[tid+192];
    #pragma unroll
    for (int k = 32; k >= 1; k >>= 1) s += __shfl_xor(s, k, 64);
    if (tid == 0) red[1] = s;
  }
  __syncthreads();
  float inv = 1.f / red[1];
  int d = tid & 63, sg = tid >> 6;
  float acc = 0.f;
  for (int s = sg*49; s < sg*49 + 49; ++s)
    acc += scL[s] * b2f(KV[(size_t)(b*S_ + s)*1024 + 512 + h*64 + d]);
  pv[sg][d] = acc;
  __syncthreads();
  if (tid < 64)
    o[b*512 + h*64 + tid] = (pv[0][tid] + pv[1][tid] + pv[2][tid] + pv[3][tid]) * inv;
}

// attn = o @ Wo + bo, written as bf16 into synapse-input cols [0,512)
__global__ __launch_bounds__(256) void attnproj(const float* __restrict__ o,
    const float* __restrict__ Wo, const float* __restrict__ bo_p,
    short* __restrict__ preb)
{
  __shared__ float ov[512];
  int b = blockIdx.x, tid = threadIdx.x;
  for (int j = tid; j < 512; j += 256) ov[j] = o[b*512 + j];
  __syncthreads();
  int n0 = tid, n1 = tid + 256;
  float a0 = 0.f, a1 = 0.f;
  #pragma unroll 8
  for (int k = 0; k < 512; ++k) {
    float v = ov[k];
    a0 += v * Wo[k*512+n0];
    a1 += v * Wo[k*512+n1];
  }
  preb[(size_t)b*1536 + n0] = f2b(a0 + bo_p[n0]);
  preb[(size_t)b*1536 + n1] = f2b(a1 + bo_p[n1]);
}

// GLU + LayerNorm(1024) -> hist ring slot (f32). One block per b.
__global__ __launch_bounds__(256) void glu_ln(const float* __restrict__ g,
    const float* __restrict__ gsyn, const float* __restrict__ bsyn_ln,
    float* __restrict__ hist, int t)
{
  __shared__ float wred[4][2];
  int b = blockIdx.x, tid = threadIdx.x;
  float uv[4]; float s = 0.f, s2 = 0.f;
  #pragma unroll
  for (int k2 = 0; k2 < 4; ++k2) {
    int i = tid + k2*256;
    float a_ = g[(size_t)b*2048 + i];
    float bg = g[(size_t)b*2048 + 1024 + i];
    float u = a_ * (1.f / (1.f + expf(-bg)));
    uv[k2] = u; s += u; s2 += u*u;
  }
  #pragma unroll
  for (int m = 1; m < 64; m <<= 1) { s += __shfl_xor(s, m, 64); s2 += __shfl_xor(s2, m, 64); }
  int w = tid >> 6;
  if ((tid & 63) == 0) { wred[w][0] = s; wred[w][1] = s2; }
  __syncthreads();
  float S  = wred[0][0] + wred[1][0] + wred[2][0] + wred[3][0];
  float S2 = wred[0][1] + wred[1][1] + wred[2][1] + wred[3][1];
  float mean = S * (1.f/1024.f);
  float var  = S2 * (1.f/1024.f) - mean*mean;
  float inv  = rsqrtf(var + 1e-5f);
  int slot = t % MEM_;
  #pragma unroll
  for (int k2 = 0; k2 < 4; ++k2) {
    int i = tid + k2*256;
    float y = (uv[k2] - mean) * inv * gsyn[i] + bsyn_ln[i];
    hist[((size_t)i*MEM_ + slot)*64 + b] = y;
  }
}

// NLM: per-neuron MLP over the 25-deep memory window. Block = neuron, lane = b.
__global__ __launch_bounds__(64) void nlm(const float* __restrict__ hist,
    const float* __restrict__ W1, const float* __restrict__ b1,
    const float* __restrict__ W2, const float* __restrict__ b2,
    float* __restrict__ actT, short* __restrict__ preb, int t)
{
  int n = blockIdx.x, b = threadIdx.x;
  float h[32];
  #pragma unroll
  for (int j = 0; j < 32; ++j) h[j] = b1[n*32+j];
  for (int m = 0; m < MEM_; ++m) {
    int phys = (t + 1 + m) % MEM_;
    float hv = hist[((size_t)n*MEM_ + phys)*64 + b];
    const float* wp = &W1[((size_t)n*MEM_ + m)*32];
    #pragma unroll
    for (int j = 0; j < 32; ++j) h[j] += hv * wp[j];
  }
  float acc = b2[n];
  const float* w2p = &W2[n*32];
  #pragma unroll
  for (int j = 0; j < 32; ++j) {
    float hh = h[j];
    acc += (hh > 0.f ? hh : 0.f) * w2p[j];
  }
  actT[n*64 + b] = acc;
  preb[(size_t)b*1536 + 512 + n] = f2b(acc);
}

// out sync + pred = sync_o@Wout + bout + entropy certainties. Block per b.
__global__ __launch_bounds__(256) void outk(const float* __restrict__ actT,
    float* __restrict__ ao, float* __restrict__ bo_s,
    const int* __restrict__ li, const int* __restrict__ ri,
    const float* __restrict__ decay,
    const float* __restrict__ Wout, const float* __restrict__ bout,
    float* __restrict__ out, int t)
{
  __shared__ float syncL[512];
  __shared__ float predL[512];
  __shared__ float redM[1];
  __shared__ float zred[4][2];
  int b = blockIdx.x, tid = threadIdx.x;
  for (int j = tid; j < 512; j += 256) {
    float r = expf(-clip015(decay[j]));
    float prod = actT[li[j]*64 + b] * actT[ri[j]*64 + b];
    float a  = r*ao[b*512+j] + prod; ao[b*512+j] = a;
    float bb = r*bo_s[b*512+j] + 1.f; bo_s[b*512+j] = bb;
    syncL[j] = a * rsqrtf(bb);
  }
  __syncthreads();
  int n0 = tid, n1 = tid + 256;
  float a0 = 0.f, a1 = 0.f;
  #pragma unroll 8
  for (int k = 0; k < 512; ++k) {
    float sv = syncL[k];
    a0 += sv * Wout[k*512+n0];
    a1 += sv * Wout[k*512+n1];
  }
  a0 += bout[n0]; a1 += bout[n1];
  predL[n0] = a0; predL[n1] = a1;
  out[((size_t)b*512 + n0)*16 + t] = a0;
  out[((size_t)b*512 + n1)*16 + t] = a1;
  __syncthreads();
  if (tid < 64) {
    float m = -1e30f;
    for (int j = tid; j < 512; j += 64) m = fmaxf(m, predL[j]);
    #pragma unroll
    for (int k = 32; k >= 1; k >>= 1) m = fmaxf(m, __shfl_xor(m, k, 64));
    if (tid == 0) redM[0] = m;
  }
  __syncthreads();
  float M = redM[0];
  float z = 0.f, s1 = 0.f;
  for (int j = tid; j < 512; j += 256) {
    float e = expf(predL[j] - M);
    z += e; s1 += e * (predL[j] - M);
  }
  #pragma unroll
  for (int m = 1; m < 64; m <<= 1) { z += __shfl_xor(z, m, 64); s1 += __shfl_xor(s1, m, 64); }
  if ((tid & 63) == 0) { zred[tid>>6][0] = z; zred[tid>>6][1] = s1; }
  __syncthreads();
  if (tid == 0) {
    float Z  = zred[0][0] + zred[1][0] + zred[2][0] + zred[3][0];
    float S1 = zred[0][1] + zred[1][1] + zred[2][1] + zred[3][1];
    float plp = S1 / Z - logf(Z);
    float ne = -plp / logf(512.f);
    out[524288 + (size_t)b*32 + t]      = ne;
    out[524288 + (size_t)b*32 + 16 + t] = 1.f - ne;
  }
}

// Re-initialize all recurrent state (graph-replay deterministic).
__global__ __launch_bounds__(256) void initk(float* __restrict__ aa, float* __restrict__ ba,
    float* __restrict__ ao, float* __restrict__ bo_s,
    float* __restrict__ actT, float* __restrict__ hist, short* __restrict__ preb,
    const float* __restrict__ init_act, const float* __restrict__ init_hist,
    const int* __restrict__ li_o, const int* __restrict__ ri_o)
{
  int i = blockIdx.x*256 + threadIdx.x;
  if (i < 64*512) {
    aa[i] = 0.f; ba[i] = 0.f;
    int j = i & 511;
    ao[i] = init_act[li_o[j]] * init_act[ri_o[j]];
    bo_s[i] = 1.f;
  }
  if (i < 65536) {
    int n = i >> 6, b = i & 63;
    actT[i] = init_act[n];
    preb[(size_t)b*1536 + 512 + n] = f2b(init_act[n]);
  }
  if (i < DM_*MEM_*64) {
    int nm = i >> 6;
    hist[i] = init_hist[nm];
  }
}

// ---------------------------------------------------------------------------
extern "C" void kernel_launch(void* const* d_in, const int* in_sizes, int n_in,
                              void* d_out, int out_size, void* d_ws, size_t ws_size,
                              hipStream_t stream)
{
  (void)in_sizes; (void)n_in; (void)out_size; (void)ws_size;
  const float* x       = (const float*)d_in[0];
  const float* Wqp     = (const float*)d_in[1];
  const float* bqp     = (const float*)d_in[2];
  const float* Wkv     = (const float*)d_in[3];
  const float* bkv     = (const float*)d_in[4];
  const float* g_kv    = (const float*)d_in[5];
  const float* b_kv    = (const float*)d_in[6];
  const float* Wq      = (const float*)d_in[7];
  const float* bq      = (const float*)d_in[8];
  const float* Wk      = (const float*)d_in[9];
  const float* bk      = (const float*)d_in[10];
  const float* Wv      = (const float*)d_in[11];
  const float* bv      = (const float*)d_in[12];
  const float* Wo      = (const float*)d_in[13];
  const float* bo_p    = (const float*)d_in[14];
  const float* Wsyn    = (const float*)d_in[15];
  const float* bsyn    = (const float*)d_in[16];
  const float* g_syn   = (const float*)d_in[17];
  const float* b_syn   = (const float*)d_in[18];
  const float* W1      = (const float*)d_in[19];
  const float* b1      = (const float*)d_in[20];
  const float* W2      = (const float*)d_in[21];
  const float* b2      = (const float*)d_in[22];
  const float* init_act  = (const float*)d_in[23];
  const float* init_hist = (const float*)d_in[24];
  const float* decay_a = (const float*)d_in[25];
  const float* decay_o = (const float*)d_in[26];
  const float* Wout    = (const float*)d_in[27];
  const float* bout    = (const float*)d_in[28];
  const int* li_a = (const int*)d_in[29];
  const int* ri_a = (const int*)d_in[30];
  const int* li_o = (const int*)d_in[31];
  const int* ri_o = (const int*)d_in[32];

  char* ws = (char*)d_ws;
  short* xT     = (short*)(ws + 0);            // 12,845,056 B
  float* kv_pre = (float*)(ws + 12845056);     // 25,690,112 B
  short* kv     = (short*)(ws + 38535168);     // 12,845,056 B
  short* KV     = (short*)(ws + 51380224);     // 25,690,112 B
  short* WkvT   = (short*)(ws + 77070336);     //    524,288 B
  short* WkkvT  = (short*)(ws + 77594624);     //  1,048,576 B
  short* WsynT  = (short*)(ws + 78643200);     //  6,291,456 B
  float* qh     = (float*)(ws + 84934656);     //    131,072 B
  float* o_buf  = (float*)(ws + 85065728);     //    131,072 B
  short* preb   = (short*)(ws + 85196800);     //    196,608 B
  float* g_buf  = (float*)(ws + 85393408);     //    524,288 B
  float* aa     = (float*)(ws + 85917696);
  float* ba     = (float*)(ws + 86048768);
  float* ao     = (float*)(ws + 86179840);
  float* bo_s   = (float*)(ws + 86310912);
  float* actT   = (float*)(ws + 86441984);     //    262,144 B
  float* hist   = (float*)(ws + 86704128);     //  6,553,600 B  (end ~93.3 MB)

  const int BIGSPLIT = 1 << 30;

  initk<<<6400, 256, 0, stream>>>(aa, ba, ao, bo_s, actT, hist, preb,
                                  init_act, init_hist, li_o, ri_o);
  wtrans<<<dim3(16,16), 256, 0, stream>>>(Wkv, WkvT, 512, 512);
  wtrans<<<dim3(16,16), 256, 0, stream>>>(Wk, WkkvT, 512, 512);
  wtrans<<<dim3(16,16), 256, 0, stream>>>(Wv, WkkvT + (size_t)512*512, 512, 512);
  wtrans<<<dim3(64,48), 256, 0, stream>>>(Wsyn, WsynT, 1536, 2048);

  for (int t = 0; t < T_; ++t) {
    xpose_x<<<dim3(16,7,64), 256, 0, stream>>>(x, xT, t);
    gemm_k<1><<<dim3(98,4), 256, 0, stream>>>(xT, WkvT, kv_pre, bkv, bkv, BIGSPLIT,
                                              MR_, 512, 512);
    ln_rows<<<3136, 256, 0, stream>>>(kv_pre, g_kv, b_kv, kv, MR_);
    gemm_k<0><<<dim3(98,8), 256, 0, stream>>>(kv, WkkvT, KV, bk, bv, 512,
                                              MR_, 1024, 512);
    s1_q<<<64, 256, 0, stream>>>(actT, aa, ba, li_a, ri_a, decay_a,
                                 Wqp, bqp, Wq, bq, qh);
    attn_k<<<dim3(8,64), 256, 0, stream>>>(qh, KV, o_buf);
    attnproj<<<64, 256, 0, stream>>>(o_buf, Wo, bo_p, preb);
    gemm_k<1><<<dim3(1,16), 256, 0, stream>>>(preb, WsynT, g_buf, bsyn, bsyn, BIGSPLIT,
                                              64, 2048, 1536);
    glu_ln<<<64, 256, 0, stream>>>(g_buf, g_syn, b_syn, hist, t);
    nlm<<<1024, 64, 0, stream>>>(hist, W1, b1, W2, b2, actT, preb, t);
    outk<<<64, 256, 0, stream>>>(actT, ao, bo_s, li_o, ri_o, decay_o,
                                 Wout, bout, (float*)d_out, t);
  }
}

// Round 3
// 2877.626 us; speedup vs baseline: 1.2069x; 1.2069x over previous
//
#include <hip/hip_runtime.h>
#include <stdint.h>
#include <stddef.h>

#define B_    64
#define T_    16
#define DF_   512
#define S_    196
#define DIN_  512
#define H_    8
#define DH_   64
#define DM_   1024
#define MEM_  25
#define HN_   32
#define MR_   (B_*S_)   /* 12544 rows per tick */

typedef short bf16x8 __attribute__((ext_vector_type(8)));
typedef float f32x4  __attribute__((ext_vector_type(4)));

__device__ __forceinline__ float b2f(short h){
  unsigned u = ((unsigned)(unsigned short)h) << 16;
  float f; __builtin_memcpy(&f, &u, 4); return f;
}
__device__ __forceinline__ short f2b(float f){
  unsigned u; __builtin_memcpy(&u, &f, 4);
  u = (u + 0x7fffu + ((u >> 16) & 1u)) >> 16;
  return (short)(unsigned short)u;
}
__device__ __forceinline__ float clip015(float d){
  return d < 0.f ? 0.f : (d > 15.f ? 15.f : d);
}

// ---------------------------------------------------------------------------
// bf16 MFMA GEMM: C[M,N] = A[M,K]@W + bias, W passed as WT[N][K] (stride K).
// 128x128 tile, BK=64, 4 waves 2x2, 16x16x32 MFMA, global_load_lds width-16
// with XOR chunk swizzle (T21). A row stride lda, C row stride ldc.
// ---------------------------------------------------------------------------
template<int OUTF32>
__global__ __launch_bounds__(256,2) void gemm_k(
    const short* __restrict__ A, const short* __restrict__ WT,
    void* __restrict__ Cout,
    const float* __restrict__ biasA, const float* __restrict__ biasB, int nsplit,
    int M, int N, int K, int lda, int ldc)
{
  __shared__ short lA[128*64];
  __shared__ short lB[128*64];
  const int tid = threadIdx.x;
  const int w = tid >> 6, l = tid & 63;
  const int m0 = blockIdx.x * 128, n0 = blockIdx.y * 128;
  const int wm = (w >> 1) * 64, wn = (w & 1) * 64;
  f32x4 acc[4][4];
  #pragma unroll
  for (int i=0;i<4;i++)
    #pragma unroll
    for (int j=0;j<4;j++) acc[i][j] = (f32x4){0.f,0.f,0.f,0.f};

  for (int k0 = 0; k0 < K; k0 += 64) {
    #pragma unroll
    for (int rnd = 0; rnd < 4; ++rnd) {
      int cb = (rnd*4 + w) * 64;
      int slot = cb + l;
      int row = slot >> 3, kb = slot & 7;
      int kc = k0 + ((kb ^ (row & 7)) << 3);
      int gm = m0 + row; if (gm > M-1) gm = M-1;
      const short* srcA = A + (size_t)gm * lda + kc;
      __builtin_amdgcn_global_load_lds(
          (const __attribute__((address_space(1))) void*)srcA,
          (__attribute__((address_space(3))) void*)&lA[cb*8], 16, 0, 0);
      const short* srcB = WT + (size_t)(n0 + row) * K + kc;
      __builtin_amdgcn_global_load_lds(
          (const __attribute__((address_space(1))) void*)srcB,
          (__attribute__((address_space(3))) void*)&lB[cb*8], 16, 0, 0);
    }
    asm volatile("s_waitcnt vmcnt(0)" ::: "memory");
    __syncthreads();
    #pragma unroll
    for (int ks = 0; ks < 2; ++ks) {
      bf16x8 af[4], bfr[4];
      #pragma unroll
      for (int i = 0; i < 4; ++i) {
        int ra = wm + i*16 + (l & 15);
        int c  = ks*4 + (l >> 4);
        af[i]  = *(const bf16x8*)&lA[ra*64 + ((c ^ (ra & 7)) << 3)];
        int rb = wn + i*16 + (l & 15);
        bfr[i] = *(const bf16x8*)&lB[rb*64 + ((c ^ (rb & 7)) << 3)];
      }
      #pragma unroll
      for (int i = 0; i < 4; ++i)
        #pragma unroll
        for (int j = 0; j < 4; ++j)
          acc[i][j] = __builtin_amdgcn_mfma_f32_16x16x32_bf16(af[i], bfr[j], acc[i][j], 0, 0, 0);
    }
    __syncthreads();
  }
  #pragma unroll
  for (int i = 0; i < 4; ++i) {
    #pragma unroll
    for (int j = 0; j < 4; ++j) {
      int gn = n0 + wn + j*16 + (l & 15);
      float bb = biasA ? ((gn < nsplit) ? biasA[gn] : biasB[gn - nsplit]) : 0.f;
      #pragma unroll
      for (int r = 0; r < 4; ++r) {
        int gm = m0 + wm + i*16 + (l >> 4)*4 + r;
        if (gm < M) {
          float v = acc[i][j][r] + bb;
          if (OUTF32) ((float*)Cout)[(size_t)gm * ldc + gn] = v;
          else        ((short*)Cout)[(size_t)gm * ldc + gn] = f2b(v);
        }
      }
    }
  }
}

// ---------------------------------------------------------------------------
// Synapse GEMM, split-K: A=preb[64][1536] bf16, WT=WsynF[2048][1536] bf16.
// grid (16 n-blocks, 4 k-splits); each block 64x128 tile, K-slice 384.
// Writes f32 partials gpart[ksplit][64][2048] (summed + biased in glu_ln).
// ---------------------------------------------------------------------------
__global__ __launch_bounds__(256) void gemm_syn(const short* __restrict__ A,
    const short* __restrict__ WT, float* __restrict__ gpart)
{
  __shared__ short lA[64*64];
  __shared__ short lB[128*64];
  int tid = threadIdx.x, w = tid >> 6, l = tid & 63;
  int n0 = blockIdx.x * 128;
  int kb0 = blockIdx.y * 384;
  int wn = w * 32;
  f32x4 acc[4][2];
  #pragma unroll
  for (int i=0;i<4;i++){ acc[i][0]=(f32x4){0,0,0,0}; acc[i][1]=(f32x4){0,0,0,0}; }

  for (int k0 = 0; k0 < 384; k0 += 64) {
    #pragma unroll
    for (int rnd = 0; rnd < 6; ++rnd) {
      int cb = rnd*256 + w*64;
      int slot = cb + l;
      if (rnd < 2) {           // A region: slots 0..511
        int row = slot >> 3, kb = slot & 7;
        int kc = kb0 + k0 + ((kb ^ (row & 7)) << 3);
        __builtin_amdgcn_global_load_lds(
            (const __attribute__((address_space(1))) void*)(A + (size_t)row*1536 + kc),
            (__attribute__((address_space(3))) void*)&lA[cb*8], 16, 0, 0);
      } else {                 // B region: slots 512..1535
        int j = slot - 512;
        int row = j >> 3, kb = j & 7;
        int kc = kb0 + k0 + ((kb ^ (row & 7)) << 3);
        __builtin_amdgcn_global_load_lds(
            (const __attribute__((address_space(1))) void*)(WT + (size_t)(n0+row)*1536 + kc),
            (__attribute__((address_space(3))) void*)&lB[(cb-512)*8], 16, 0, 0);
      }
    }
    asm volatile("s_waitcnt vmcnt(0)" ::: "memory");
    __syncthreads();
    #pragma unroll
    for (int ks = 0; ks < 2; ++ks) {
      bf16x8 af[4], bfv[2];
      int c = ks*4 + (l >> 4);
      #pragma unroll
      for (int i = 0; i < 4; ++i) {
        int ra = i*16 + (l & 15);
        af[i] = *(const bf16x8*)&lA[ra*64 + ((c ^ (ra & 7)) << 3)];
      }
      #pragma unroll
      for (int j = 0; j < 2; ++j) {
        int rb = wn + j*16 + (l & 15);
        bfv[j] = *(const bf16x8*)&lB[rb*64 + ((c ^ (rb & 7)) << 3)];
      }
      #pragma unroll
      for (int i = 0; i < 4; ++i)
        #pragma unroll
        for (int j = 0; j < 2; ++j)
          acc[i][j] = __builtin_amdgcn_mfma_f32_16x16x32_bf16(af[i], bfv[j], acc[i][j], 0, 0, 0);
    }
    __syncthreads();
  }
  float* gp = gpart + (size_t)blockIdx.y * 64 * 2048;
  #pragma unroll
  for (int i = 0; i < 4; ++i)
    #pragma unroll
    for (int j = 0; j < 2; ++j) {
      int gn = n0 + wn + j*16 + (l & 15);
      #pragma unroll
      for (int r = 0; r < 4; ++r) {
        int gm = i*16 + (l >> 4)*4 + r;
        gp[(size_t)gm*2048 + gn] = acc[i][j][r];
      }
    }
}

// ---------------------------------------------------------------------------
// Batched transpose of x over a tick chunk: f32 [B][T][DF][S] -> bf16 rows
// ((ti*B+b)*S + s) x [DF].
// ---------------------------------------------------------------------------
__global__ __launch_bounds__(256) void xpose_x(const float* __restrict__ x,
                                               short* __restrict__ xT, int t0, int tc)
{
  __shared__ float tile[32][33];
  int df0 = blockIdx.x*32, s0 = blockIdx.y*32;
  int z = blockIdx.z;
  int b = z / tc, ti = z % tc;
  int tx = threadIdx.x & 31, ty = threadIdx.x >> 5;
  const float* src = x + (size_t)(b*T_ + t0 + ti) * DF_ * S_;
  #pragma unroll
  for (int i = 0; i < 4; ++i) {
    int df = df0 + ty + i*8;
    int s  = s0 + tx;
    tile[ty+i*8][tx] = (s < S_) ? src[(size_t)df*S_ + s] : 0.f;
  }
  __syncthreads();
  short* dst = xT + (size_t)(ti*B_ + b) * S_ * DIN_;
  #pragma unroll
  for (int i = 0; i < 4; ++i) {
    int s  = s0 + ty + i*8;
    int df = df0 + tx;
    if (s < S_) dst[(size_t)s*DF_ + df] = f2b(tile[tx][ty+i*8]);
  }
}

// Weight transpose f32->bf16: out[(c)*ldo + coff + r] = in[r][c]
__global__ __launch_bounds__(256) void wtrans(const float* __restrict__ in,
    short* __restrict__ out, int R, int C, int ldo, int coff)
{
  __shared__ float tile[32][33];
  int c0 = blockIdx.x*32, r0 = blockIdx.y*32;
  int tx = threadIdx.x & 31, ty = threadIdx.x >> 5;
  #pragma unroll
  for (int i = 0; i < 4; ++i)
    tile[ty+i*8][tx] = in[(size_t)(r0+ty+i*8)*C + c0+tx];
  __syncthreads();
  #pragma unroll
  for (int i = 0; i < 4; ++i)
    out[(size_t)(c0+ty+i*8)*ldo + coff + r0+tx] = f2b(tile[tx][ty+i*8]);
}

// f32 -> bf16 flat copy
__global__ __launch_bounds__(256) void cvtb(const float* __restrict__ in,
                                            short* __restrict__ out, int n)
{
  int i = blockIdx.x*256 + threadIdx.x;
  if (i < n) out[i] = f2b(in[i]);
}

// out[n] = base[n] + sum_k vec[k]*W[k*ldw+n]
__global__ __launch_bounds__(256) void bias_fold(const float* __restrict__ vec,
    const float* __restrict__ W, const float* __restrict__ base,
    float* __restrict__ out, int N, int ldw)
{
  int n = blockIdx.x*256 + threadIdx.x;
  if (n >= N) return;
  float a = base[n];
  #pragma unroll 8
  for (int k = 0; k < 512; ++k) a += vec[k]*W[(size_t)k*ldw + n];
  out[n] = a;
}

// Row LayerNorm over 512 cols: bf16 in -> bf16 out. One wave per row.
__global__ __launch_bounds__(256) void ln_rows(const short* __restrict__ in,
    const float* __restrict__ g, const float* __restrict__ bta,
    short* __restrict__ out, int nrows)
{
  int w = threadIdx.x >> 6, l = threadIdx.x & 63;
  int r = blockIdx.x*4 + w;
  if (r >= nrows) return;
  bf16x8 v8 = *(const bf16x8*)&in[(size_t)r*512 + l*8];
  float v[8]; float s = 0.f, s2 = 0.f;
  #pragma unroll
  for (int j = 0; j < 8; ++j) { v[j] = b2f(v8[j]); s += v[j]; s2 += v[j]*v[j]; }
  #pragma unroll
  for (int m = 1; m < 64; m <<= 1) { s += __shfl_xor(s, m, 64); s2 += __shfl_xor(s2, m, 64); }
  float mean = s * (1.f/512.f);
  float var  = s2 * (1.f/512.f) - mean*mean;
  float inv  = rsqrtf(var + 1e-5f);
  bf16x8 o8;
  #pragma unroll
  for (int j = 0; j < 8; ++j)
    o8[j] = f2b((v[j] - mean) * inv * g[l*8+j] + bta[l*8+j]);
  *(bf16x8*)&out[(size_t)r*512 + l*8] = o8;
}

// ---------------------------------------------------------------------------
// Fused per-tick: sync_a update -> qh = sync@Wqq + bqh -> 8-head attention
// -> unprojected o written bf16 into preb[:,0:512]. Block per b, 512 thr.
// ---------------------------------------------------------------------------
__global__ __launch_bounds__(512) void tick_attn(const float* __restrict__ actT,
    float* __restrict__ aa, float* __restrict__ ba,
    const int* __restrict__ li, const int* __restrict__ ri,
    const float* __restrict__ decay,
    const float* __restrict__ Wqq, const float* __restrict__ bqh,
    const short* __restrict__ KV, short* __restrict__ preb, int ti)
{
  __shared__ float syncL[512];
  __shared__ float qhL[512];
  __shared__ float pL[8][256];
  int b = blockIdx.x, tid = threadIdx.x;
  {
    int j = tid;
    float r = expf(-clip015(decay[j]));
    float prod = actT[li[j]*64 + b] * actT[ri[j]*64 + b];
    float a  = r*aa[b*512+j] + prod; aa[b*512+j] = a;
    float bb = r*ba[b*512+j] + 1.f;  ba[b*512+j] = bb;
    syncL[j] = a * rsqrtf(bb);
  }
  __syncthreads();
  {
    int m = tid;
    float a = bqh[m];
    #pragma unroll 8
    for (int k = 0; k < 512; ++k) a += syncL[k]*Wqq[(size_t)k*512 + m];
    qhL[m] = a;
  }
  __syncthreads();
  int h = tid >> 6, l = tid & 63;
  const short* base = KV + (size_t)(ti*B_ + b) * S_ * 1024;
  float sc[4];
  #pragma unroll
  for (int r4 = 0; r4 < 4; ++r4) {
    int s = r4*64 + l;
    int sL = s < S_ ? s : S_-1;
    const short* kp = base + (size_t)sL*1024 + h*64;
    float a = 0.f;
    #pragma unroll
    for (int c = 0; c < 8; ++c) {
      bf16x8 kk = *(const bf16x8*)&kp[c*8];
      #pragma unroll
      for (int j = 0; j < 8; ++j) a += qhL[h*64 + c*8 + j] * b2f(kk[j]);
    }
    sc[r4] = (s < S_) ? a * 0.125f : -1e30f;
  }
  float mx = fmaxf(fmaxf(sc[0], sc[1]), fmaxf(sc[2], sc[3]));
  #pragma unroll
  for (int k = 32; k >= 1; k >>= 1) mx = fmaxf(mx, __shfl_xor(mx, k, 64));
  float ps = 0.f;
  #pragma unroll
  for (int r4 = 0; r4 < 4; ++r4) {
    float p = expf(sc[r4] - mx);
    ps += p;
    pL[h][r4*64 + l] = p;
  }
  #pragma unroll
  for (int k = 32; k >= 1; k >>= 1) ps += __shfl_xor(ps, k, 64);
  float inv = 1.f / ps;
  float acc = 0.f;
  #pragma unroll 4
  for (int s = 0; s < S_; ++s)
    acc += pL[h][s] * b2f(base[(size_t)s*1024 + 512 + h*64 + l]);
  preb[(size_t)b*1536 + h*64 + l] = f2b(acc * inv);
}

// GLU + LN(1024): sums 4 split-K partials + folded bias -> hist ring slot.
__global__ __launch_bounds__(256) void glu_ln(const float* __restrict__ gpart,
    const float* __restrict__ bsynF,
    const float* __restrict__ gsyn, const float* __restrict__ bln,
    float* __restrict__ hist, int t)
{
  __shared__ float wred[4][2];
  int b = blockIdx.x, tid = threadIdx.x;
  float uv[4]; float s = 0.f, s2 = 0.f;
  #pragma unroll
  for (int k2 = 0; k2 < 4; ++k2) {
    int i = tid + k2*256;
    float a_ = bsynF[i];
    float bg = bsynF[1024 + i];
    #pragma unroll
    for (int z = 0; z < 4; ++z) {
      a_ += gpart[(size_t)z*131072 + b*2048 + i];
      bg += gpart[(size_t)z*131072 + b*2048 + 1024 + i];
    }
    float u = a_ * (1.f / (1.f + expf(-bg)));
    uv[k2] = u; s += u; s2 += u*u;
  }
  #pragma unroll
  for (int m = 1; m < 64; m <<= 1) { s += __shfl_xor(s, m, 64); s2 += __shfl_xor(s2, m, 64); }
  int w = tid >> 6;
  if ((tid & 63) == 0) { wred[w][0] = s; wred[w][1] = s2; }
  __syncthreads();
  float S  = wred[0][0] + wred[1][0] + wred[2][0] + wred[3][0];
  float S2 = wred[0][1] + wred[1][1] + wred[2][1] + wred[3][1];
  float mean = S * (1.f/1024.f);
  float var  = S2 * (1.f/1024.f) - mean*mean;
  float inv  = rsqrtf(var + 1e-5f);
  int slot = t % MEM_;
  #pragma unroll
  for (int k2 = 0; k2 < 4; ++k2) {
    int i = tid + k2*256;
    float y = (uv[k2] - mean) * inv * gsyn[i] + bln[i];
    hist[((size_t)i*MEM_ + slot)*64 + b] = y;
  }
}

// NLM: per-neuron MLP over memory window. Block = neuron, lane = b.
__global__ __launch_bounds__(64) void nlm(const float* __restrict__ hist,
    const float* __restrict__ W1, const float* __restrict__ b1,
    const float* __restrict__ W2, const float* __restrict__ b2,
    float* __restrict__ actT, short* __restrict__ preb, int t)
{
  int n = blockIdx.x, b = threadIdx.x;
  float h[32];
  #pragma unroll
  for (int j = 0; j < 32; ++j) h[j] = b1[n*32+j];
  for (int m = 0; m < MEM_; ++m) {
    int phys = (t + 1 + m) % MEM_;
    float hv = hist[((size_t)n*MEM_ + phys)*64 + b];
    const float* wp = &W1[((size_t)n*MEM_ + m)*32];
    #pragma unroll
    for (int j = 0; j < 32; ++j) h[j] += hv * wp[j];
  }
  float acc = b2[n];
  const float* w2p = &W2[n*32];
  #pragma unroll
  for (int j = 0; j < 32; ++j) {
    float hh = h[j];
    acc += (hh > 0.f ? hh : 0.f) * w2p[j];
  }
  actT[n*64 + b] = acc;
  preb[(size_t)b*1536 + 512 + n] = f2b(acc);
}

// out sync + pred = sync_o@Wout + bout + entropy certainties. Block per b.
__global__ __launch_bounds__(256) void outk(const float* __restrict__ actT,
    float* __restrict__ ao, float* __restrict__ bo_s,
    const int* __restrict__ li, const int* __restrict__ ri,
    const float* __restrict__ decay,
    const float* __restrict__ Wout, const float* __restrict__ bout,
    float* __restrict__ out, int t)
{
  __shared__ float syncL[512];
  __shared__ float predL[512];
  __shared__ float redM[1];
  __shared__ float zred[4][2];
  int b = blockIdx.x, tid = threadIdx.x;
  for (int j = tid; j < 512; j += 256) {
    float r = expf(-clip015(decay[j]));
    float prod = actT[li[j]*64 + b] * actT[ri[j]*64 + b];
    float a  = r*ao[b*512+j] + prod; ao[b*512+j] = a;
    float bb = r*bo_s[b*512+j] + 1.f; bo_s[b*512+j] = bb;
    syncL[j] = a * rsqrtf(bb);
  }
  __syncthreads();
  int n0 = tid, n1 = tid + 256;
  float a0 = 0.f, a1 = 0.f;
  #pragma unroll 8
  for (int k = 0; k < 512; ++k) {
    float sv = syncL[k];
    a0 += sv * Wout[k*512+n0];
    a1 += sv * Wout[k*512+n1];
  }
  a0 += bout[n0]; a1 += bout[n1];
  predL[n0] = a0; predL[n1] = a1;
  out[((size_t)b*512 + n0)*16 + t] = a0;
  out[((size_t)b*512 + n1)*16 + t] = a1;
  __syncthreads();
  if (tid < 64) {
    float m = -1e30f;
    for (int j = tid; j < 512; j += 64) m = fmaxf(m, predL[j]);
    #pragma unroll
    for (int k = 32; k >= 1; k >>= 1) m = fmaxf(m, __shfl_xor(m, k, 64));
    if (tid == 0) redM[0] = m;
  }
  __syncthreads();
  float M = redM[0];
  float z = 0.f, s1 = 0.f;
  for (int j = tid; j < 512; j += 256) {
    float e = expf(predL[j] - M);
    z += e; s1 += e * (predL[j] - M);
  }
  #pragma unroll
  for (int m = 1; m < 64; m <<= 1) { z += __shfl_xor(z, m, 64); s1 += __shfl_xor(s1, m, 64); }
  if ((tid & 63) == 0) { zred[tid>>6][0] = z; zred[tid>>6][1] = s1; }
  __syncthreads();
  if (tid == 0) {
    float Z  = zred[0][0] + zred[1][0] + zred[2][0] + zred[3][0];
    float S1 = zred[0][1] + zred[1][1] + zred[2][1] + zred[3][1];
    float plp = S1 / Z - logf(Z);
    float ne = -plp / logf(512.f);
    out[524288 + (size_t)b*32 + t]      = ne;
    out[524288 + (size_t)b*32 + 16 + t] = 1.f - ne;
  }
}

// Re-initialize all recurrent state (graph-replay deterministic).
__global__ __launch_bounds__(256) void initk(float* __restrict__ aa, float* __restrict__ ba,
    float* __restrict__ ao, float* __restrict__ bo_s,
    float* __restrict__ actT, float* __restrict__ hist, short* __restrict__ preb,
    const float* __restrict__ init_act, const float* __restrict__ init_hist,
    const int* __restrict__ li_o, const int* __restrict__ ri_o)
{
  int i = blockIdx.x*256 + threadIdx.x;
  if (i < 64*512) {
    aa[i] = 0.f; ba[i] = 0.f;
    int j = i & 511;
    ao[i] = init_act[li_o[j]] * init_act[ri_o[j]];
    bo_s[i] = 1.f;
  }
  if (i < 65536) {
    int n = i >> 6, b = i & 63;
    actT[i] = init_act[n];
    preb[(size_t)b*1536 + 512 + n] = f2b(init_act[n]);
  }
  if (i < DM_*MEM_*64) {
    int nm = i >> 6;
    hist[i] = init_hist[nm];
  }
}

// ---------------------------------------------------------------------------
extern "C" void kernel_launch(void* const* d_in, const int* in_sizes, int n_in,
                              void* d_out, int out_size, void* d_ws, size_t ws_size,
                              hipStream_t stream)
{
  (void)in_sizes; (void)n_in; (void)out_size;
  const float* x       = (const float*)d_in[0];
  const float* Wqp     = (const float*)d_in[1];
  const float* bqp     = (const float*)d_in[2];
  const float* Wkv     = (const float*)d_in[3];
  const float* bkv     = (const float*)d_in[4];
  const float* g_kv    = (const float*)d_in[5];
  const float* b_kv    = (const float*)d_in[6];
  const float* Wq      = (const float*)d_in[7];
  const float* bq      = (const float*)d_in[8];
  const float* Wk      = (const float*)d_in[9];
  const float* bk      = (const float*)d_in[10];
  const float* Wv      = (const float*)d_in[11];
  const float* bv      = (const float*)d_in[12];
  const float* Wo      = (const float*)d_in[13];
  const float* bo_p    = (const float*)d_in[14];
  const float* Wsyn    = (const float*)d_in[15];
  const float* bsyn    = (const float*)d_in[16];
  const float* g_syn   = (const float*)d_in[17];
  const float* b_syn   = (const float*)d_in[18];
  const float* W1      = (const float*)d_in[19];
  const float* b1      = (const float*)d_in[20];
  const float* W2      = (const float*)d_in[21];
  const float* b2      = (const float*)d_in[22];
  const float* init_act  = (const float*)d_in[23];
  const float* init_hist = (const float*)d_in[24];
  const float* decay_a = (const float*)d_in[25];
  const float* decay_o = (const float*)d_in[26];
  const float* Wout    = (const float*)d_in[27];
  const float* bout    = (const float*)d_in[28];
  const int* li_a = (const int*)d_in[29];
  const int* ri_a = (const int*)d_in[30];
  const int* li_o = (const int*)d_in[31];
  const int* ri_o = (const int*)d_in[32];

  // ---- fixed small region at the START of ws ----
  char* ws = (char*)d_ws;
  size_t off = 0;
  auto alloc = [&](size_t bytes) { char* p = ws + off; off += (bytes + 255) & ~(size_t)255; return p; };
  short* WkvT   = (short*)alloc(512*512*2);
  short* WkkvT  = (short*)alloc(1024*512*2);
  short* WsynF  = (short*)alloc(2048*1536*2);
  short* WsynTt = (short*)alloc(2048*512*2);
  short* WqpB   = (short*)alloc(512*512*2);
  short* WqT    = (short*)alloc(512*512*2);
  short* WoB    = (short*)alloc(512*512*2);
  float* Wqq    = (float*)alloc(512*512*4);
  float* bqh    = (float*)alloc(512*4);
  float* bsynF  = (float*)alloc(2048*4);
  short* preb   = (short*)alloc(64*1536*2);
  float* gpart  = (float*)alloc(4*64*2048*4);
  float* aa     = (float*)alloc(64*512*4);
  float* ba     = (float*)alloc(64*512*4);
  float* ao     = (float*)alloc(64*512*4);
  float* bo_s   = (float*)alloc(64*512*4);
  float* actT   = (float*)alloc(1024*64*4);
  float* hist   = (float*)alloc((size_t)1024*25*64*4);
  size_t fixed_end = off;

  // ---- per-tick big buffers: chunked to fit ws_size ----
  const size_t PT_XT = (size_t)MR_*512*2;   // 12,845,056
  const size_t PT_KV = (size_t)MR_*1024*2;  // 25,690,112
  const size_t per_tick = PT_XT*3 + PT_KV;  // xT + kvp + kv + KV
  size_t avail = (ws_size > fixed_end) ? ws_size - fixed_end : 0;
  int tc = (int)(avail / per_tick);
  if (tc > T_) tc = T_;
  if (tc < 1) tc = 1;   // requires ws_size >= ~87 MB

  short* xT  = (short*)(ws + fixed_end);
  short* kvp = (short*)((char*)xT  + PT_XT*tc);
  short* kv  = (short*)((char*)kvp + PT_XT*tc);
  short* KV  = (short*)((char*)kv  + PT_XT*tc);

  const int BIG = 1 << 30;

  initk<<<6400, 256, 0, stream>>>(aa, ba, ao, bo_s, actT, hist, preb,
                                  init_act, init_hist, li_o, ri_o);
  // weight prep + algebraic folds
  wtrans<<<dim3(16,16), 256, 0, stream>>>(Wkv, WkvT, 512, 512, 512, 0);
  wtrans<<<dim3(16,16), 256, 0, stream>>>(Wk,  WkkvT, 512, 512, 512, 0);
  wtrans<<<dim3(16,16), 256, 0, stream>>>(Wv,  WkkvT + (size_t)512*512, 512, 512, 512, 0);
  wtrans<<<dim3(64,32), 256, 0, stream>>>(Wsyn + (size_t)512*2048, WsynF, 1024, 2048, 1536, 512);
  wtrans<<<dim3(64,16), 256, 0, stream>>>(Wsyn, WsynTt, 512, 2048, 512, 0);
  wtrans<<<dim3(16,16), 256, 0, stream>>>(Wq,  WqT, 512, 512, 512, 0);
  cvtb<<<1024, 256, 0, stream>>>(Wqp, WqpB, 512*512);
  cvtb<<<1024, 256, 0, stream>>>(Wo,  WoB,  512*512);
  // Wqq = Wqp @ Wq  (f32 out)
  gemm_k<1><<<dim3(4,4), 256, 0, stream>>>(WqpB, WqT, Wqq, nullptr, nullptr, BIG,
                                           512, 512, 512, 512, 512);
  // WsynF[:, 0:512] = (Wsyn_top^T) @ (Wo^T)   [bf16 out, ldc=1536]
  gemm_k<0><<<dim3(16,4), 256, 0, stream>>>(WsynTt, WoB, WsynF, nullptr, nullptr, BIG,
                                            2048, 512, 512, 512, 1536);
  bias_fold<<<2, 256, 0, stream>>>(bqp,  Wq,   bq,   bqh,   512,  512);
  bias_fold<<<8, 256, 0, stream>>>(bo_p, Wsyn, bsyn, bsynF, 2048, 2048);

  for (int t0 = 0; t0 < T_; t0 += tc) {
    int tcc = (t0 + tc <= T_) ? tc : (T_ - t0);
    int Mc = MR_ * tcc;
    // batched t-independent pipeline for this chunk
    xpose_x<<<dim3(16,7,B_*tcc), 256, 0, stream>>>(x, xT, t0, tcc);
    gemm_k<0><<<dim3(98*tcc,4), 256, 0, stream>>>(xT, WkvT, kvp, bkv, bkv, BIG,
                                                  Mc, 512, 512, 512, 512);
    ln_rows<<<3136*tcc, 256, 0, stream>>>(kvp, g_kv, b_kv, kv, Mc);
    gemm_k<0><<<dim3(98*tcc,8), 256, 0, stream>>>(kv, WkkvT, KV, bk, bv, 512,
                                                  Mc, 1024, 512, 512, 1024);
    // serial per-tick chain
    for (int ti = 0; ti < tcc; ++ti) {
      int t = t0 + ti;
      tick_attn<<<64, 512, 0, stream>>>(actT, aa, ba, li_a, ri_a, decay_a,
                                        Wqq, bqh, KV, preb, ti);
      gemm_syn<<<dim3(16,4), 256, 0, stream>>>(preb, WsynF, gpart);
      glu_ln<<<64, 256, 0, stream>>>(gpart, bsynF, g_syn, b_syn, hist, t);
      nlm<<<1024, 64, 0, stream>>>(hist, W1, b1, W2, b2, actT, preb, t);
      outk<<<64, 256, 0, stream>>>(actT, ao, bo_s, li_o, ri_o, decay_o,
                                   Wout, bout, (float*)d_out, t);
    }
  }
}

// Round 5
// 2840.610 us; speedup vs baseline: 1.2227x; 1.0130x over previous
//
#include <hip/hip_runtime.h>
#include <stdint.h>
#include <stddef.h>

#define B_    64
#define T_    16
#define DF_   512
#define S_    196
#define DIN_  512
#define H_    8
#define DH_   64
#define DM_   1024
#define MEM_  25
#define HN_   32
#define MR_   (B_*S_)   /* 12544 rows per tick */

typedef short bf16x8 __attribute__((ext_vector_type(8)));
typedef float f32x4  __attribute__((ext_vector_type(4)));

__device__ __forceinline__ float b2f(short h){
  unsigned u = ((unsigned)(unsigned short)h) << 16;
  float f; __builtin_memcpy(&f, &u, 4); return f;
}
__device__ __forceinline__ short f2b(float f){
  unsigned u; __builtin_memcpy(&u, &f, 4);
  u = (u + 0x7fffu + ((u >> 16) & 1u)) >> 16;
  return (short)(unsigned short)u;
}
__device__ __forceinline__ float clip015(float d){
  return d < 0.f ? 0.f : (d > 15.f ? 15.f : d);
}

// ---------------------------------------------------------------------------
// bf16 MFMA GEMM with 2-phase prefetch double-buffer (catalog T3-minimum):
// C[M,N] = A[M,K]@W + bias, W passed as WT[N][K]. 128x128 tile, BK=64,
// 4 waves 2x2, 16x16x32 MFMA, global_load_lds width-16, XOR chunk swizzle.
// __syncthreads() implicitly drains vmcnt(0), so buffer `cur` is ready after
// the barrier; next tile's loads are issued right after and fly under MFMA.
// ---------------------------------------------------------------------------
template<int OUTF32>
__global__ __launch_bounds__(256,2) void gemm_k(
    const short* __restrict__ A, const short* __restrict__ WT,
    void* __restrict__ Cout,
    const float* __restrict__ biasA, const float* __restrict__ biasB, int nsplit,
    int M, int N, int K, int lda, int ldc)
{
  __shared__ short lA[2][128*64];
  __shared__ short lB[2][128*64];
  const int tid = threadIdx.x;
  const int w = tid >> 6, l = tid & 63;
  const int m0 = blockIdx.x * 128, n0 = blockIdx.y * 128;
  const int wm = (w >> 1) * 64, wn = (w & 1) * 64;
  f32x4 acc[4][4];
  #pragma unroll
  for (int i=0;i<4;i++)
    #pragma unroll
    for (int j=0;j<4;j++) acc[i][j] = (f32x4){0.f,0.f,0.f,0.f};

  auto stage = [&](int buf, int k0) {
    #pragma unroll
    for (int rnd = 0; rnd < 4; ++rnd) {
      int cb = (rnd*4 + w) * 64;
      int slot = cb + l;
      int row = slot >> 3, kb = slot & 7;
      int kc = k0 + ((kb ^ (row & 7)) << 3);
      int gm = m0 + row; if (gm > M-1) gm = M-1;
      __builtin_amdgcn_global_load_lds(
          (const __attribute__((address_space(1))) void*)(A + (size_t)gm * lda + kc),
          (__attribute__((address_space(3))) void*)&lA[buf][cb*8], 16, 0, 0);
      __builtin_amdgcn_global_load_lds(
          (const __attribute__((address_space(1))) void*)(WT + (size_t)(n0 + row) * K + kc),
          (__attribute__((address_space(3))) void*)&lB[buf][cb*8], 16, 0, 0);
    }
  };

  const int nk = K >> 6;
  stage(0, 0);
  int cur = 0;
  for (int kt = 0; kt < nk; ++kt) {
    __syncthreads();                       // drains vmcnt(0): buf `cur` ready
    if (kt + 1 < nk) stage(cur ^ 1, (kt + 1) << 6);   // prefetch under compute
    #pragma unroll
    for (int ks = 0; ks < 2; ++ks) {
      bf16x8 af[4], bfr[4];
      #pragma unroll
      for (int i = 0; i < 4; ++i) {
        int ra = wm + i*16 + (l & 15);
        int c  = ks*4 + (l >> 4);
        af[i]  = *(const bf16x8*)&lA[cur][ra*64 + ((c ^ (ra & 7)) << 3)];
        int rb = wn + i*16 + (l & 15);
        bfr[i] = *(const bf16x8*)&lB[cur][rb*64 + ((c ^ (rb & 7)) << 3)];
      }
      #pragma unroll
      for (int i = 0; i < 4; ++i)
        #pragma unroll
        for (int j = 0; j < 4; ++j)
          acc[i][j] = __builtin_amdgcn_mfma_f32_16x16x32_bf16(af[i], bfr[j], acc[i][j], 0, 0, 0);
    }
    cur ^= 1;
  }
  #pragma unroll
  for (int i = 0; i < 4; ++i) {
    #pragma unroll
    for (int j = 0; j < 4; ++j) {
      int gn = n0 + wn + j*16 + (l & 15);
      float bb = biasA ? ((gn < nsplit) ? biasA[gn] : biasB[gn - nsplit]) : 0.f;
      #pragma unroll
      for (int r = 0; r < 4; ++r) {
        int gm = m0 + wm + i*16 + (l >> 4)*4 + r;
        if (gm < M) {
          float v = acc[i][j][r] + bb;
          if (OUTF32) ((float*)Cout)[(size_t)gm * ldc + gn] = v;
          else        ((short*)Cout)[(size_t)gm * ldc + gn] = f2b(v);
        }
      }
    }
  }
}

// ---------------------------------------------------------------------------
// Batched transpose of x over a tick chunk: f32 [B][T][DF][S] -> bf16 rows
// ((ti*B+b)*S + s) x [DF].
// ---------------------------------------------------------------------------
__global__ __launch_bounds__(256) void xpose_x(const float* __restrict__ x,
                                               short* __restrict__ xT, int t0, int tc)
{
  __shared__ float tile[32][33];
  int df0 = blockIdx.x*32, s0 = blockIdx.y*32;
  int z = blockIdx.z;
  int b = z / tc, ti = z % tc;
  int tx = threadIdx.x & 31, ty = threadIdx.x >> 5;
  const float* src = x + (size_t)(b*T_ + t0 + ti) * DF_ * S_;
  #pragma unroll
  for (int i = 0; i < 4; ++i) {
    int df = df0 + ty + i*8;
    int s  = s0 + tx;
    tile[ty+i*8][tx] = (s < S_) ? src[(size_t)df*S_ + s] : 0.f;
  }
  __syncthreads();
  short* dst = xT + (size_t)(ti*B_ + b) * S_ * DIN_;
  #pragma unroll
  for (int i = 0; i < 4; ++i) {
    int s  = s0 + ty + i*8;
    int df = df0 + tx;
    if (s < S_) dst[(size_t)s*DF_ + df] = f2b(tile[tx][ty+i*8]);
  }
}

// Weight transpose f32->bf16: out[c*ldo + coff + r] = in[r][c]
__global__ __launch_bounds__(256) void wtrans(const float* __restrict__ in,
    short* __restrict__ out, int R, int C, int ldo, int coff)
{
  __shared__ float tile[32][33];
  int c0 = blockIdx.x*32, r0 = blockIdx.y*32;
  int tx = threadIdx.x & 31, ty = threadIdx.x >> 5;
  #pragma unroll
  for (int i = 0; i < 4; ++i)
    tile[ty+i*8][tx] = in[(size_t)(r0+ty+i*8)*C + c0+tx];
  __syncthreads();
  #pragma unroll
  for (int i = 0; i < 4; ++i)
    out[(size_t)(c0+ty+i*8)*ldo + coff + r0+tx] = f2b(tile[tx][ty+i*8]);
}

// f32 -> bf16 flat copy
__global__ __launch_bounds__(256) void cvtb(const float* __restrict__ in,
                                            short* __restrict__ out, int n)
{
  int i = blockIdx.x*256 + threadIdx.x;
  if (i < n) out[i] = f2b(in[i]);
}

// out[n] = base[n] + sum_k vec[k]*W[k*ldw+n]
__global__ __launch_bounds__(256) void bias_fold(const float* __restrict__ vec,
    const float* __restrict__ W, const float* __restrict__ base,
    float* __restrict__ out, int N, int ldw)
{
  int n = blockIdx.x*256 + threadIdx.x;
  if (n >= N) return;
  float a = base[n];
  #pragma unroll 8
  for (int k = 0; k < 512; ++k) a += vec[k]*W[(size_t)k*ldw + n];
  out[n] = a;
}

// Row permutation of WsynF so GLU pairs land in the same MFMA fragment:
// dest row r (= blk*16+i) <- orig col (i<8 ? blk*8+i : 1024+blk*8+i-8)
__global__ __launch_bounds__(256) void permrows(const short* __restrict__ in,
                                                short* __restrict__ out)
{
  int r = blockIdx.x;
  int k = r >> 4, i = r & 15;
  int src = (i < 8) ? (k*8 + i) : (1024 + k*8 + (i - 8));
  const bf16x8* s = (const bf16x8*)(in + (size_t)src*1536);
  bf16x8* d = (bf16x8*)(out + (size_t)r*1536);
  int j = threadIdx.x;
  if (j < 192) d[j] = s[j];
}

// Row LayerNorm over 512 cols: bf16 in -> bf16 out. One wave per row.
__global__ __launch_bounds__(256) void ln_rows(const short* __restrict__ in,
    const float* __restrict__ g, const float* __restrict__ bta,
    short* __restrict__ out, int nrows)
{
  int w = threadIdx.x >> 6, l = threadIdx.x & 63;
  int r = blockIdx.x*4 + w;
  if (r >= nrows) return;
  bf16x8 v8 = *(const bf16x8*)&in[(size_t)r*512 + l*8];
  float v[8]; float s = 0.f, s2 = 0.f;
  #pragma unroll
  for (int j = 0; j < 8; ++j) { v[j] = b2f(v8[j]); s += v[j]; s2 += v[j]*v[j]; }
  #pragma unroll
  for (int m = 1; m < 64; m <<= 1) { s += __shfl_xor(s, m, 64); s2 += __shfl_xor(s2, m, 64); }
  float mean = s * (1.f/512.f);
  float var  = s2 * (1.f/512.f) - mean*mean;
  float inv  = rsqrtf(var + 1e-5f);
  bf16x8 o8;
  #pragma unroll
  for (int j = 0; j < 8; ++j)
    o8[j] = f2b((v[j] - mean) * inv * g[l*8+j] + bta[l*8+j]);
  *(bf16x8*)&out[(size_t)r*512 + l*8] = o8;
}

// ---------------------------------------------------------------------------
// outk body (shared): 512 threads, one block per b. Computes out-sync,
// pred, entropy for tick tt.
// ---------------------------------------------------------------------------
__device__ __forceinline__ void outk_body(int tt, int b, int tid,
    float* syncL, float* wred,
    const float* actT, float* ao, float* bo_s,
    const int* li_o, const int* ri_o, const float* decay_o,
    const float* Wout, const float* bout, float* out)
{
  int j = tid;
  float rr = expf(-clip015(decay_o[j]));
  float prod = actT[li_o[j]*64 + b] * actT[ri_o[j]*64 + b];
  float a2 = rr*ao[b*512+j] + prod; ao[b*512+j] = a2;
  float bb2 = rr*bo_s[b*512+j] + 1.f; bo_s[b*512+j] = bb2;
  syncL[j] = a2 * rsqrtf(bb2);
  __syncthreads();
  float a = bout[j];
  #pragma unroll 8
  for (int k = 0; k < 512; ++k) a += syncL[k]*Wout[k*512+j];
  out[((size_t)b*512 + j)*16 + tt] = a;
  int w = tid >> 6, l = tid & 63;
  float m = a;
  #pragma unroll
  for (int k = 32; k >= 1; k >>= 1) m = fmaxf(m, __shfl_xor(m, k, 64));
  if (l == 0) wred[w] = m;
  __syncthreads();
  float M = wred[0];
  #pragma unroll
  for (int k = 1; k < 8; ++k) M = fmaxf(M, wred[k]);
  float e = expf(a - M);
  float z = e, s1 = e*(a - M);
  #pragma unroll
  for (int k = 32; k >= 1; k >>= 1) { z += __shfl_xor(z, k, 64); s1 += __shfl_xor(s1, k, 64); }
  if (l == 0) { wred[8+w] = z; wred[16+w] = s1; }
  __syncthreads();
  if (tid == 0) {
    float Z = 0.f, S1 = 0.f;
    #pragma unroll
    for (int k = 0; k < 8; ++k) { Z += wred[8+k]; S1 += wred[16+k]; }
    float plp = S1 / Z - logf(Z);
    float ne = -plp * (1.f/logf(512.f));
    out[524288 + (size_t)b*32 + tt]      = ne;
    out[524288 + (size_t)b*32 + 16 + tt] = 1.f - ne;
  }
}

// ---------------------------------------------------------------------------
// tick_ao: blocks 0-63 = attn(t) for b=bid; blocks 64-127 = outk(t-1).
// The two halves are data-independent (attn reads actT, aa/ba; outk reads
// actT, ao/bo_s) -> no grid barrier needed.
// ---------------------------------------------------------------------------
__global__ __launch_bounds__(512) void tick_ao(
    const float* __restrict__ actT,
    float* __restrict__ aa, float* __restrict__ ba,
    const int* __restrict__ li_a, const int* __restrict__ ri_a,
    const float* __restrict__ decay_a,
    const float* __restrict__ Wqq, const float* __restrict__ bqh,
    const short* __restrict__ KV, short* __restrict__ preb,
    float* __restrict__ ao, float* __restrict__ bo_s,
    const int* __restrict__ li_o, const int* __restrict__ ri_o,
    const float* __restrict__ decay_o,
    const float* __restrict__ Wout, const float* __restrict__ bout,
    float* __restrict__ out, int t, int ti)
{
  __shared__ __attribute__((aligned(16))) float smem[3072];
  const int bid = blockIdx.x, tid = threadIdx.x;
  if (bid < 64) {
    int b = bid;
    float* syncL = smem;
    float* qhL   = smem + 512;
    float* pL    = smem + 1024;   // 8*256
    int j = tid;
    float rr = expf(-clip015(decay_a[j]));
    float prod = actT[li_a[j]*64 + b] * actT[ri_a[j]*64 + b];
    float a2 = rr*aa[b*512+j] + prod; aa[b*512+j] = a2;
    float bb2 = rr*ba[b*512+j] + 1.f;  ba[b*512+j] = bb2;
    syncL[j] = a2 * rsqrtf(bb2);
    __syncthreads();
    float qa = bqh[j];
    #pragma unroll 8
    for (int k = 0; k < 512; ++k) qa += syncL[k]*Wqq[(size_t)k*512 + j];
    qhL[j] = qa;
    __syncthreads();
    int h = tid >> 6, l = tid & 63;
    const short* base = KV + (size_t)(ti*B_ + b) * S_ * 1024;
    float sc[4];
    #pragma unroll
    for (int r4 = 0; r4 < 4; ++r4) {
      int s = r4*64 + l;
      int sL = s < S_ ? s : S_-1;
      const short* kp = base + (size_t)sL*1024 + h*64;
      float a = 0.f;
      #pragma unroll
      for (int c = 0; c < 8; ++c) {
        bf16x8 kk = *(const bf16x8*)&kp[c*8];
        #pragma unroll
        for (int jj = 0; jj < 8; ++jj) a += qhL[h*64 + c*8 + jj] * b2f(kk[jj]);
      }
      sc[r4] = (s < S_) ? a * 0.125f : -1e30f;
    }
    float mx = fmaxf(fmaxf(sc[0], sc[1]), fmaxf(sc[2], sc[3]));
    #pragma unroll
    for (int k = 32; k >= 1; k >>= 1) mx = fmaxf(mx, __shfl_xor(mx, k, 64));
    float ps = 0.f;
    #pragma unroll
    for (int r4 = 0; r4 < 4; ++r4) {
      float p = expf(sc[r4] - mx);
      ps += p;
      pL[h*256 + r4*64 + l] = p;
    }
    #pragma unroll
    for (int k = 32; k >= 1; k >>= 1) ps += __shfl_xor(ps, k, 64);
    float inv = 1.f / ps;
    float accv = 0.f;
    #pragma unroll 4
    for (int s = 0; s < S_; ++s)
      accv += pL[h*256 + s] * b2f(base[(size_t)s*1024 + 512 + h*64 + l]);
    preb[(size_t)b*1536 + h*64 + l] = f2b(accv * inv);
  } else if (t > 0) {
    outk_body(t-1, bid-64, tid, smem, smem+512, actT, ao, bo_s,
              li_o, ri_o, decay_o, Wout, bout, out);
  }
}

// Final outk for t = T-1.
__global__ __launch_bounds__(512) void outk_fin(
    const float* __restrict__ actT,
    float* __restrict__ ao, float* __restrict__ bo_s,
    const int* __restrict__ li_o, const int* __restrict__ ri_o,
    const float* __restrict__ decay_o,
    const float* __restrict__ Wout, const float* __restrict__ bout,
    float* __restrict__ out)
{
  __shared__ __attribute__((aligned(16))) float smem[544];
  outk_body(T_-1, blockIdx.x, threadIdx.x, smem, smem+512, actT, ao, bo_s,
            li_o, ri_o, decay_o, Wout, bout, out);
}

// ---------------------------------------------------------------------------
// syn_glu: synapse GEMM (full K=1536, no split) + GLU -> u[64][1024].
// 128 blocks x 512 thr. Block bid owns 16 permuted weight rows
// (= 8 GLU (a,gate) col pairs). 8 waves = 4 m-fragments x 2 K-halves.
// ---------------------------------------------------------------------------
__global__ __launch_bounds__(512) void syn_glu(const short* __restrict__ preb,
    const short* __restrict__ WsynP, const float* __restrict__ bsynF,
    float* __restrict__ u)
{
  __shared__ f32x4 part[512];
  const int bid = blockIdx.x, tid = threadIdx.x;
  int w = tid >> 6, l = tid & 63;
  int mf = w & 3, kh = w >> 2;
  int arow = mf*16 + (l & 15);
  int kbase = kh*768 + (l >> 4)*8;
  const short* ap = preb + (size_t)arow*1536 + kbase;
  const short* bp = WsynP + (size_t)(bid*16 + (l & 15))*1536 + kbase;
  f32x4 acc = (f32x4){0.f,0.f,0.f,0.f};
  #pragma unroll 4
  for (int ks = 0; ks < 24; ++ks) {
    bf16x8 av = *(const bf16x8*)(ap + ks*32);
    bf16x8 bv = *(const bf16x8*)(bp + ks*32);
    acc = __builtin_amdgcn_mfma_f32_16x16x32_bf16(av, bv, acc, 0, 0, 0);
  }
  part[w*64 + l] = acc;
  __syncthreads();
  if (w < 4) {
    f32x4 o1 = part[w*64 + l], o2 = part[(w+4)*64 + l];
    int c = l & 15;
    int colg = bid*8 + (c & 7);
    float bias = (c < 8) ? bsynF[colg] : bsynF[1024 + colg];
    float tv[4], pv[4];
    #pragma unroll
    for (int r2 = 0; r2 < 4; ++r2) tv[r2] = o1[r2] + o2[r2] + bias;
    #pragma unroll
    for (int r2 = 0; r2 < 4; ++r2) pv[r2] = __shfl_xor(tv[r2], 8, 64);
    if (c < 8) {
      #pragma unroll
      for (int r2 = 0; r2 < 4; ++r2) {
        float uu = tv[r2] * (1.f/(1.f + expf(-pv[r2])));
        int brow = w*16 + (l >> 4)*4 + r2;
        u[brow*1024 + colg] = uu;
      }
    }
  }
}

// ---------------------------------------------------------------------------
// nlm_ln: per-batch LN stats over u (computed redundantly per block from L2),
// write new hist slot, run NLM -> actT + preb[:,512:]. 128 blocks x 512 thr;
// block bid owns neurons bid*8..bid*8+7 for all 64 batches.
// ---------------------------------------------------------------------------
__global__ __launch_bounds__(512) void nlm_ln(const float* __restrict__ u,
    const float* __restrict__ gsyn, const float* __restrict__ bln,
    float* __restrict__ hist,
    const float* __restrict__ W1, const float* __restrict__ b1,
    const float* __restrict__ W2, const float* __restrict__ b2,
    float* __restrict__ actT, short* __restrict__ preb, int t)
{
  __shared__ float mstat[64], istat[64];
  const int bid = blockIdx.x, tid = threadIdx.x;
  {
    int b = tid >> 3, p = tid & 7;
    const float* up = u + b*1024 + p*128;
    float s = 0.f, s2 = 0.f;
    #pragma unroll 8
    for (int i = 0; i < 128; ++i) { float v = up[i]; s += v; s2 += v*v; }
    #pragma unroll
    for (int k = 4; k >= 1; k >>= 1) { s += __shfl_xor(s, k, 64); s2 += __shfl_xor(s2, k, 64); }
    if (p == 0) {
      float mean = s * (1.f/1024.f);
      float var  = s2 * (1.f/1024.f) - mean*mean;
      mstat[b] = mean;
      istat[b] = rsqrtf(var + 1e-5f);
    }
  }
  __syncthreads();
  int n = (bid << 3) + (tid >> 6), b = tid & 63;
  float nv = (u[b*1024 + n] - mstat[b]) * istat[b] * gsyn[n] + bln[n];
  int slot = t % MEM_;
  hist[((size_t)n*MEM_ + slot)*64 + b] = nv;
  float h[32];
  #pragma unroll
  for (int j = 0; j < 32; ++j) h[j] = b1[n*32+j];
  #pragma unroll 5
  for (int m = 0; m < MEM_; ++m) {
    int phys = (t + 1 + m) % MEM_;
    float hv = (m == MEM_-1) ? nv : hist[((size_t)n*MEM_ + phys)*64 + b];
    const float* wp = &W1[((size_t)n*MEM_ + m)*32];
    #pragma unroll
    for (int j = 0; j < 32; ++j) h[j] += hv * wp[j];
  }
  float acc = b2[n];
  #pragma unroll
  for (int j = 0; j < 32; ++j) acc += fmaxf(h[j], 0.f) * W2[n*32+j];
  actT[n*64 + b] = acc;
  preb[(size_t)b*1536 + 512 + n] = f2b(acc);
}

// Re-initialize all recurrent state (graph-replay deterministic).
__global__ __launch_bounds__(256) void initk(float* __restrict__ aa, float* __restrict__ ba,
    float* __restrict__ ao, float* __restrict__ bo_s,
    float* __restrict__ actT, float* __restrict__ hist, short* __restrict__ preb,
    const float* __restrict__ init_act, const float* __restrict__ init_hist,
    const int* __restrict__ li_o, const int* __restrict__ ri_o)
{
  int i = blockIdx.x*256 + threadIdx.x;
  if (i < 64*512) {
    aa[i] = 0.f; ba[i] = 0.f;
    int j = i & 511;
    ao[i] = init_act[li_o[j]] * init_act[ri_o[j]];
    bo_s[i] = 1.f;
  }
  if (i < 65536) {
    int n = i >> 6, b = i & 63;
    actT[i] = init_act[n];
    preb[(size_t)b*1536 + 512 + n] = f2b(init_act[n]);
  }
  if (i < DM_*MEM_*64) {
    int nm = i >> 6;
    hist[i] = init_hist[nm];
  }
}

// ---------------------------------------------------------------------------
extern "C" void kernel_launch(void* const* d_in, const int* in_sizes, int n_in,
                              void* d_out, int out_size, void* d_ws, size_t ws_size,
                              hipStream_t stream)
{
  (void)in_sizes; (void)n_in; (void)out_size;
  const float* x       = (const float*)d_in[0];
  const float* Wqp     = (const float*)d_in[1];
  const float* bqp     = (const float*)d_in[2];
  const float* Wkv     = (const float*)d_in[3];
  const float* bkv     = (const float*)d_in[4];
  const float* g_kv    = (const float*)d_in[5];
  const float* b_kv    = (const float*)d_in[6];
  const float* Wq      = (const float*)d_in[7];
  const float* bq      = (const float*)d_in[8];
  const float* Wk      = (const float*)d_in[9];
  const float* bk      = (const float*)d_in[10];
  const float* Wv      = (const float*)d_in[11];
  const float* bv      = (const float*)d_in[12];
  const float* Wo      = (const float*)d_in[13];
  const float* bo_p    = (const float*)d_in[14];
  const float* Wsyn    = (const float*)d_in[15];
  const float* bsyn    = (const float*)d_in[16];
  const float* g_syn   = (const float*)d_in[17];
  const float* b_syn   = (const float*)d_in[18];
  const float* W1      = (const float*)d_in[19];
  const float* b1      = (const float*)d_in[20];
  const float* W2      = (const float*)d_in[21];
  const float* b2      = (const float*)d_in[22];
  const float* init_act  = (const float*)d_in[23];
  const float* init_hist = (const float*)d_in[24];
  const float* decay_a = (const float*)d_in[25];
  const float* decay_o = (const float*)d_in[26];
  const float* Wout    = (const float*)d_in[27];
  const float* bout    = (const float*)d_in[28];
  const int* li_a = (const int*)d_in[29];
  const int* ri_a = (const int*)d_in[30];
  const int* li_o = (const int*)d_in[31];
  const int* ri_o = (const int*)d_in[32];

  char* ws = (char*)d_ws;
  size_t off = 0;
  auto alloc = [&](size_t bytes) { char* p = ws + off; off += (bytes + 255) & ~(size_t)255; return p; };
  short* WkvT   = (short*)alloc(512*512*2);
  short* WkkvT  = (short*)alloc(1024*512*2);
  short* WsynF  = (short*)alloc(2048*1536*2);
  short* WsynP  = (short*)alloc(2048*1536*2);
  short* WsynTt = (short*)alloc(2048*512*2);
  short* WqpB   = (short*)alloc(512*512*2);
  short* WqT    = (short*)alloc(512*512*2);
  short* WoB    = (short*)alloc(512*512*2);
  float* Wqq    = (float*)alloc(512*512*4);
  float* bqh    = (float*)alloc(512*4);
  float* bsynF  = (float*)alloc(2048*4);
  short* preb   = (short*)alloc(64*1536*2);
  float* u      = (float*)alloc(64*1024*4);
  float* aa     = (float*)alloc(64*512*4);
  float* ba     = (float*)alloc(64*512*4);
  float* ao     = (float*)alloc(64*512*4);
  float* bo_s   = (float*)alloc(64*512*4);
  float* actT   = (float*)alloc(1024*64*4);
  float* hist   = (float*)alloc((size_t)1024*25*64*4);
  size_t fixed_end = off;

  const size_t PT_XT = (size_t)MR_*512*2;
  const size_t PT_KV = (size_t)MR_*1024*2;
  const size_t per_tick = PT_XT*3 + PT_KV;
  size_t avail = (ws_size > fixed_end) ? ws_size - fixed_end : 0;
  int tc = (int)(avail / per_tick);
  if (tc > T_) tc = T_;
  if (tc < 1) tc = 1;

  short* xT  = (short*)(ws + fixed_end);
  short* kvp = (short*)((char*)xT  + PT_XT*tc);
  short* kv  = (short*)((char*)kvp + PT_XT*tc);
  short* KV  = (short*)((char*)kv  + PT_XT*tc);

  const int BIG = 1 << 30;

  initk<<<6400, 256, 0, stream>>>(aa, ba, ao, bo_s, actT, hist, preb,
                                  init_act, init_hist, li_o, ri_o);
  wtrans<<<dim3(16,16), 256, 0, stream>>>(Wkv, WkvT, 512, 512, 512, 0);
  wtrans<<<dim3(16,16), 256, 0, stream>>>(Wk,  WkkvT, 512, 512, 512, 0);
  wtrans<<<dim3(16,16), 256, 0, stream>>>(Wv,  WkkvT + (size_t)512*512, 512, 512, 512, 0);
  wtrans<<<dim3(64,32), 256, 0, stream>>>(Wsyn + (size_t)512*2048, WsynF, 1024, 2048, 1536, 512);
  wtrans<<<dim3(64,16), 256, 0, stream>>>(Wsyn, WsynTt, 512, 2048, 512, 0);
  wtrans<<<dim3(16,16), 256, 0, stream>>>(Wq,  WqT, 512, 512, 512, 0);
  cvtb<<<1024, 256, 0, stream>>>(Wqp, WqpB, 512*512);
  cvtb<<<1024, 256, 0, stream>>>(Wo,  WoB,  512*512);
  gemm_k<1><<<dim3(4,4), 256, 0, stream>>>(WqpB, WqT, Wqq, nullptr, nullptr, BIG,
                                           512, 512, 512, 512, 512);
  gemm_k<0><<<dim3(16,4), 256, 0, stream>>>(WsynTt, WoB, WsynF, nullptr, nullptr, BIG,
                                            2048, 512, 512, 512, 1536);
  permrows<<<2048, 256, 0, stream>>>(WsynF, WsynP);
  bias_fold<<<2, 256, 0, stream>>>(bqp,  Wq,   bq,   bqh,   512,  512);
  bias_fold<<<8, 256, 0, stream>>>(bo_p, Wsyn, bsyn, bsynF, 2048, 2048);

  for (int t0 = 0; t0 < T_; t0 += tc) {
    int tcc = (t0 + tc <= T_) ? tc : (T_ - t0);
    int Mc = MR_ * tcc;
    xpose_x<<<dim3(16,7,B_*tcc), 256, 0, stream>>>(x, xT, t0, tcc);
    gemm_k<0><<<dim3(98*tcc,4), 256, 0, stream>>>(xT, WkvT, kvp, bkv, bkv, BIG,
                                                  Mc, 512, 512, 512, 512);
    ln_rows<<<3136*tcc, 256, 0, stream>>>(kvp, g_kv, b_kv, kv, Mc);
    gemm_k<0><<<dim3(98*tcc,8), 256, 0, stream>>>(kv, WkkvT, KV, bk, bv, 512,
                                                  Mc, 1024, 512, 512, 1024);
    for (int ti = 0; ti < tcc; ++ti) {
      int t = t0 + ti;
      tick_ao<<<128, 512, 0, stream>>>(actT, aa, ba, li_a, ri_a, decay_a,
                                       Wqq, bqh, KV, preb,
                                       ao, bo_s, li_o, ri_o, decay_o,
                                       Wout, bout, (float*)d_out, t, ti);
      syn_glu<<<128, 512, 0, stream>>>(preb, WsynP, bsynF, u);
      nlm_ln<<<128, 512, 0, stream>>>(u, g_syn, b_syn, hist,
                                      W1, b1, W2, b2, actT, preb, t);
    }
  }
  outk_fin<<<64, 512, 0, stream>>>(actT, ao, bo_s, li_o, ri_o, decay_o,
                                   Wout, bout, (float*)d_out);
}